// Round 3
// baseline (10420.174 us; speedup 1.0000x reference)
//
#include <hip/hip_runtime.h>
#include <cstddef>
#include <cstdint>

#define BB 16
#define TT 1024
#define HH 512
#define R1S 4   // h1 ring slots
#define R2S 2   // h2 ring slots

typedef __attribute__((address_space(1))) const unsigned int GBUF;
typedef __attribute__((address_space(3))) unsigned int LBUF;

// async global->LDS, 16 B/lane; LDS dst = wave-uniform base + lane*16 (x / h0 only)
__device__ __forceinline__ void gl_lds16(const float* g, float* l) {
    __builtin_amdgcn_global_load_lds((GBUF*)g, (LBUF*)l, 16, 0, 0);
}

// ballot-poll one 128-flag bank: wait until flags[base..base+127] all >= need
__device__ __forceinline__ void poll_bank(const int* flags, int base, int need) {
    const int lane = threadIdx.x & 63;
    for (;;) {
        int a = __hip_atomic_load(&flags[base + lane],      __ATOMIC_RELAXED, __HIP_MEMORY_SCOPE_AGENT);
        int b = __hip_atomic_load(&flags[base + lane + 64], __ATOMIC_RELAXED, __HIP_MEMORY_SCOPE_AGENT);
        if (__ballot((a >= need) && (b >= need)) == ~0ull) break;
        __builtin_amdgcn_s_sleep(1);
    }
}

// Stage one 256-float k-half of all 16 rows (16 KB) from an agent-coherent ring:
// sc1 loads (bypass non-coherent per-XCD L2, read at LLC) -> VGPRs -> ds_write_b128.
// Own-wave stages, own-wave reads: in-wave vmcnt/program-order LDS suffice. No fences.
__device__ __forceinline__ void stage_half_sc1(const float* src, float* dstlds,
                                               int p, int lane) {
    const float* g = src    + p * 256 + lane * 4;
    float*       l = dstlds + p * 256 + lane * 4;
    float4 v[16];
    #pragma unroll
    for (int b = 0; b < 16; ++b) {
        const float* gp = g + (size_t)b * HH;
        asm volatile("global_load_dwordx4 %0, %1, off sc1"
                     : "=v"(v[b]) : "v"(gp));
    }
    asm volatile("s_waitcnt vmcnt(0)" ::: "memory");
    #pragma unroll
    for (int b = 0; b < 16; ++b)
        *(float4*)(l + (size_t)b * HH) = v[b];
}

// fast gates: v_exp + v_rcp instead of libm tanhf / fdiv
__device__ __forceinline__ float sigmoid_f(float v) {
    return __builtin_amdgcn_rcpf(1.f + __expf(-v));
}
__device__ __forceinline__ float tanh_f(float v) {
    const float e = __expf(-2.f * fabsf(v));
    const float r = 1.f - 2.f * e * __builtin_amdgcn_rcpf(1.f + e);
    return copysignf(r, v);
}

// 256 WGs x 256 threads, 1 WG/CU. layer = wg>>7, lw = wg&127 owns h cols lw*4..+3.
// R8 = R7 compute + 2-barrier step:
//   B1: partial writes -> reduce reads            (__syncthreads)
//   B2: gval writes -> gates reads; also orders reduce-reads(t) before
//       partial-writes(t+1) and gates-reads(t) before gval-writes(t+1)
//       [writes only occur after ALL waves pass B1(t+1)]
//   B3 removed. Gates/publish/release/flag owned by wv1 only; wv0/wv2 issue the
//   x(t+1) prefetch right after B2 (latency overlaps next step's poll window).
__global__ __launch_bounds__(256, 1)
void lstm2_flow9(const float* __restrict__ x,
                 const float* __restrict__ h0,
                 const float* __restrict__ c0,
                 const float* __restrict__ w_ih0, const float* __restrict__ w_hh0,
                 const float* __restrict__ b_ih0, const float* __restrict__ b_hh0,
                 const float* __restrict__ w_ih1, const float* __restrict__ w_hh1,
                 const float* __restrict__ b_ih1, const float* __restrict__ b_hh1,
                 float* __restrict__ out,
                 int*   __restrict__ flags,    // [256] zeroed pre-launch; [0..127]=L0, [128..255]=L1
                 float* __restrict__ h1ring,   // [R1S][BB][HH]
                 float* __restrict__ h2ring)   // [R2S][BB][HH]
{
    __shared__ float act0[2 * BB * HH];   // L0: x(t) double-buffered; L1: h1(t) in slot 0
    __shared__ float act1[BB * HH];       // own h(t-1)
    __shared__ float partial[16 * 16 * 33];   // [row16][b16][32 slots + pad]
    __shared__ float gval[16 * 16];
    __shared__ float bias_lds[16];

    const int tid   = threadIdx.x;
    const int wg    = blockIdx.x;
    const int layer = wg >> 7;
    const int lw    = wg & 127;

    const float* w_in  = layer ? w_ih1 : w_ih0;
    const float* w_rec = layer ? w_hh1 : w_hh0;
    const float* b_in  = layer ? b_ih1 : b_ih0;
    const float* b_rec = layer ? b_hh1 : b_hh0;
    float* ring_own    = layer ? h2ring : h1ring;
    const int rmask    = layer ? (R2S - 1) : (R1S - 1);

    const int lane = tid & 63;
    const int wv   = tid >> 6;     // 0..3
    const int mat  = wv & 1;       // 0: input matrix, 1: recurrent matrix
    const int p    = wv >> 1;      // k half
    const int kc   = lane & 7;     // k-chunk: floats kc*4 + q*32, q=0..7
    const int r2   = lane >> 3;    // row-pair 0..7 -> rows 2*r2, 2*r2+1

    // ---- one-time: weights -> 64 VGPRs/thread (2 rows x 8 float4) ----
    float4 wreg[2][8];
    {
        #pragma unroll
        for (int i = 0; i < 2; ++i) {
            const int r = r2 * 2 + i;
            const int gate = r >> 2, jj = r & 3;
            const int grow = gate * HH + lw * 4 + jj;
            const float* wsrc = (mat ? w_rec : w_in) + (size_t)grow * HH + p * 256 + kc * 4;
            #pragma unroll
            for (int q = 0; q < 8; ++q)
                wreg[i][q] = *(const float4*)(wsrc + q * 32);
        }
    }
    if (tid < 16) {
        const int g2 = tid >> 2, j2 = tid & 3;
        const int gr = g2 * HH + lw * 4 + j2;
        bias_lds[tid] = b_in[gr] + b_rec[gr];
    }
    // c state lives in wv1 (the gates/publish wave)
    float c_reg = 0.f;
    if (wv == 1) {
        const int jj = lane & 3, b = lane >> 2;
        c_reg = c0[(size_t)layer * BB * HH + (size_t)b * HH + lw * 4 + jj];
    }
    // pre-stage x(0) (L0, input waves): each wave stages its own k-columns of all b rows
    if (layer == 0 && mat == 0) {
        #pragma unroll
        for (int b = 0; b < 16; ++b)
            gl_lds16(x + ((size_t)b * TT) * HH + p * 256 + lane * 4,
                     act0 + b * HH + p * 256);
    }
    __syncthreads();

    // slot rotation: bijective per row (sum over slots is order-free); spreads the
    // per-instruction partial-write banks 2-way (free) instead of 8-way.
    const int slot = ((mat << 4) + (p << 3) + kc + (r2 << 2)) & 31;

    auto compute_half = [&](const float* abase) {
        const float* ab0 = abase + p * 256 + kc * 4;
        float* pw0 = partial + (size_t)((r2 * 2 + 0) * 16) * 33 + slot;
        float* pw1 = partial + (size_t)((r2 * 2 + 1) * 16) * 33 + slot;
        for (int b = 0; b < 16; ++b) {
            const float* ab = ab0 + (size_t)b * HH;
            float x0 = 0.f, y0 = 0.f, z0 = 0.f, w0 = 0.f;
            float x1 = 0.f, y1 = 0.f, z1 = 0.f, w1 = 0.f;
            #pragma unroll
            for (int q = 0; q < 8; ++q) {
                float4 av = *(const float4*)(ab + q * 32);
                x0 += wreg[0][q].x * av.x;
                y0 += wreg[0][q].y * av.y;
                z0 += wreg[0][q].z * av.z;
                w0 += wreg[0][q].w * av.w;
                x1 += wreg[1][q].x * av.x;
                y1 += wreg[1][q].y * av.y;
                z1 += wreg[1][q].z * av.z;
                w1 += wreg[1][q].w * av.w;
            }
            pw0[b * 33] = (x0 + y0) + (z0 + w0);
            pw1[b * 33] = (x1 + y1) + (z1 + w1);
        }
    };

    for (int t = 0; t < TT; ++t) {
        // ======== phase A: per-wave specialized (no cross-wave deps) ========
        if (mat == 0) {
            if (layer == 1) {
                poll_bank(flags, 0, t + 1);                    // h1(t) published by all L0
                const float* s0 = h1ring + (size_t)(t & (R1S - 1)) * BB * HH;
                stage_half_sc1(s0, act0, p, lane);
            }
            asm volatile("s_waitcnt vmcnt(0)" ::: "memory");   // x prefetch (L0) staged
            compute_half(act0 + ((layer == 0) ? (t & 1) * BB * HH : 0));
        } else {
            if (t == 0) {
                const float* s1 = h0 + (size_t)layer * BB * HH;
                #pragma unroll
                for (int b = 0; b < 16; ++b)
                    gl_lds16(s1 + (size_t)b * HH + p * 256 + lane * 4,
                             act1 + b * HH + p * 256);
                asm volatile("s_waitcnt vmcnt(0)" ::: "memory");
            } else {
                if (layer == 0) {
                    poll_bank(flags, 0, t);                    // h1(t-1) published
                    if (t >= R1S) poll_bank(flags, 128, t - (R1S - 1));  // ring safety
                } else {
                    poll_bank(flags, 128, t);                  // h2(t-1) published
                }
                const float* s1 = ring_own + (size_t)((t - 1) & rmask) * BB * HH;
                stage_half_sc1(s1, act1, p, lane);
            }
            compute_half(act1);
        }
        __syncthreads();   // B1: partial ds_writes (lgkm) -> reduce reads

        // ======== reduce (all 256 threads) ========
        {
            const int rr = tid >> 4, b = tid & 15;
            const float* pp = partial + (size_t)(rr * 16 + b) * 33;
            float s0 = bias_lds[rr], s1 = 0.f, s2 = 0.f, s3 = 0.f;
            #pragma unroll
            for (int q = 0; q < 32; q += 4) {
                s0 += pp[q + 0];
                s1 += pp[q + 1];
                s2 += pp[q + 2];
                s3 += pp[q + 3];
            }
            gval[rr * 16 + b] = (s0 + s1) + (s2 + s3);
        }
        __syncthreads();   // B2: gval -> gates; also fences partial reuse for t+1

        // ======== post-B2: wave-specialized tails, no further barrier ========
        // x(t+1) prefetch first (wv0/wv2): overlaps wv1's gates+publish and the
        // next step's poll window. Same wave writes/reads its own act0 slot.
        if (layer == 0 && mat == 0 && t + 1 < TT) {
            float* l0 = act0 + ((t + 1) & 1) * BB * HH;
            #pragma unroll
            for (int b = 0; b < 16; ++b)
                gl_lds16(x + ((size_t)b * TT + (t + 1)) * HH + p * 256 + lane * 4,
                         l0 + b * HH + p * 256);
        }
        if (wv == 1) {
            const int jj = lane & 3, b = lane >> 2;
            const float gi = gval[(0  + jj) * 16 + b];
            const float gf = gval[(4  + jj) * 16 + b];
            const float gg = gval[(8  + jj) * 16 + b];
            const float go = gval[(12 + jj) * 16 + b];
            const float i_ = sigmoid_f(gi);
            const float f_ = sigmoid_f(gf);
            const float g_ = tanh_f(gg);
            const float o_ = sigmoid_f(go);
            c_reg = f_ * c_reg + i_ * g_;
            const float h_ = o_ * tanh_f(c_reg);
            // publish: agent-scope relaxed store -> write-through at LLC
            float* dst = ring_own + (size_t)(t & rmask) * BB * HH + (size_t)b * HH + lw * 4 + jj;
            __hip_atomic_store(dst, h_, __ATOMIC_RELAXED, __HIP_MEMORY_SCOPE_AGENT);
            if (t == TT - 1)
                out[(size_t)layer * BB * HH + (size_t)b * HH + lw * 4 + jj] = h_;
            // hand-built release: h stores complete at LLC, then flag store
            asm volatile("s_waitcnt vmcnt(0)" ::: "memory");
            if (lane == 0)
                __hip_atomic_store(&flags[wg], t + 1, __ATOMIC_RELAXED, __HIP_MEMORY_SCOPE_AGENT);
        }
        // no B3: next step's B1 provides the only needed cross-wave ordering
    }
}

extern "C" void kernel_launch(void* const* d_in, const int* in_sizes, int n_in,
                              void* d_out, int out_size, void* d_ws, size_t ws_size,
                              hipStream_t stream) {
    const float* xp   = (const float*)d_in[0];
    const float* h0p  = (const float*)d_in[1];
    const float* c0p  = (const float*)d_in[2];
    const float* wih0 = (const float*)d_in[3];
    const float* whh0 = (const float*)d_in[4];
    const float* bih0 = (const float*)d_in[5];
    const float* bhh0 = (const float*)d_in[6];
    const float* wih1 = (const float*)d_in[7];
    const float* whh1 = (const float*)d_in[8];
    const float* bih1 = (const float*)d_in[9];
    const float* bhh1 = (const float*)d_in[10];
    float* outp = (float*)d_out;

    int*   flags  = (int*)d_ws;                        // [256]
    float* h1ring = (float*)d_ws + 1024;               // 4 KB offset; 128 KB
    float* h2ring = h1ring + R1S * BB * HH;            // 64 KB

    hipMemsetAsync(d_ws, 0, 4096, stream);             // zero flags

    void* args[] = { &xp, &h0p, &c0p, &wih0, &whh0, &bih0, &bhh0,
                     &wih1, &whh1, &bih1, &bhh1, &outp, &flags, &h1ring, &h2ring };
    hipLaunchCooperativeKernel(lstm2_flow9, dim3(256), dim3(256), args, 0, stream);
}

// Round 4
// 7172.023 us; speedup vs baseline: 1.4529x; 1.4529x over previous
//
#include <hip/hip_runtime.h>
#include <cstddef>
#include <cstdint>

#define BB 16
#define TT 1024
#define HH 512
#define R1S 4   // h1 ring slots
#define R2S 2   // h2 ring slots

typedef __attribute__((address_space(1))) const unsigned int GBUF;
typedef __attribute__((address_space(3))) unsigned int LBUF;

// async global->LDS, 16 B/lane; LDS dst = wave-uniform base + lane*16 (x / h0 only)
__device__ __forceinline__ void gl_lds16(const float* g, float* l) {
    __builtin_amdgcn_global_load_lds((GBUF*)g, (LBUF*)l, 16, 0, 0);
}

// ballot-poll one 128-flag bank: wait until flags[base..base+127] all >= need
__device__ __forceinline__ void poll_bank(const int* flags, int base, int need) {
    const int lane = threadIdx.x & 63;
    for (;;) {
        int a = __hip_atomic_load(&flags[base + lane],      __ATOMIC_RELAXED, __HIP_MEMORY_SCOPE_AGENT);
        int b = __hip_atomic_load(&flags[base + lane + 64], __ATOMIC_RELAXED, __HIP_MEMORY_SCOPE_AGENT);
        if (__ballot((a >= need) && (b >= need)) == ~0ull) break;
        __builtin_amdgcn_s_sleep(1);
    }
}

// Stage one 256-float k-half of all 16 rows (16 KB) from an agent-coherent ring:
// sc1 loads (bypass non-coherent per-XCD L2, read at LLC) -> VGPRs -> ds_write_b128.
// Own-wave stages, own-wave reads: in-wave vmcnt/program-order LDS suffice. No fences.
__device__ __forceinline__ void stage_half_sc1(const float* src, float* dstlds,
                                               int p, int lane) {
    const float* g = src    + p * 256 + lane * 4;
    float*       l = dstlds + p * 256 + lane * 4;
    float4 v[16];
    #pragma unroll
    for (int b = 0; b < 16; ++b) {
        const float* gp = g + (size_t)b * HH;
        asm volatile("global_load_dwordx4 %0, %1, off sc1"
                     : "=v"(v[b]) : "v"(gp));
    }
    asm volatile("s_waitcnt vmcnt(0)" ::: "memory");
    #pragma unroll
    for (int b = 0; b < 16; ++b)
        *(float4*)(l + (size_t)b * HH) = v[b];
}

// fast gates (R8-proven numerics): v_exp + v_rcp instead of libm tanhf / fdiv
__device__ __forceinline__ float sigmoid_f(float v) {
    return __builtin_amdgcn_rcpf(1.f + __expf(-v));
}
__device__ __forceinline__ float tanh_f(float v) {
    const float e = __expf(-2.f * fabsf(v));
    const float r = 1.f - 2.f * e * __builtin_amdgcn_rcpf(1.f + e);
    return copysignf(r, v);
}

// 256 WGs x 256 threads, 1 WG/CU. layer = wg>>7, lw = wg&127 owns h cols lw*4..+3.
// R9 = R7 skeleton shape (polls begin together after the post-publish barrier)
// with the reduce+gates+publish FUSED into one parallel phase on all 4 waves:
//   phase A -> B1 -> fused{reduce,shfl-gather,gates,publish,drain,counter/flag}
//           -> x-prefetch issue -> B2' -> loop
// gval + B2 + serial gates eliminated. Single flag/WG released by the LAST wave
// (monotone LDS counter after each wave's own vmcnt(0) drain) so poll traffic
// is identical to R7 (the R8 regression suspect was extra poll spin/traffic).
__global__ __launch_bounds__(256, 1)
void lstm2_flow10(const float* __restrict__ x,
                  const float* __restrict__ h0,
                  const float* __restrict__ c0,
                  const float* __restrict__ w_ih0, const float* __restrict__ w_hh0,
                  const float* __restrict__ b_ih0, const float* __restrict__ b_hh0,
                  const float* __restrict__ w_ih1, const float* __restrict__ w_hh1,
                  const float* __restrict__ b_ih1, const float* __restrict__ b_hh1,
                  float* __restrict__ out,
                  int*   __restrict__ flags,    // [256] zeroed pre-launch; [0..127]=L0, [128..255]=L1
                  float* __restrict__ h1ring,   // [R1S][BB][HH]
                  float* __restrict__ h2ring)   // [R2S][BB][HH]
{
    __shared__ float act0[2 * BB * HH];       // L0: x(t) double-buffered; L1: h1(t) in slot 0
    __shared__ float act1[BB * HH];           // own h(t-1)
    __shared__ float partial[16 * 16 * 33];   // [b16][row16][32 slots + pad]
    __shared__ float bias_lds[16];
    __shared__ int   wdone;                   // monotone wave-completion counter

    const int tid   = threadIdx.x;
    const int wg    = blockIdx.x;
    const int layer = wg >> 7;
    const int lw    = wg & 127;

    const float* w_in  = layer ? w_ih1 : w_ih0;
    const float* w_rec = layer ? w_hh1 : w_hh0;
    const float* b_in  = layer ? b_ih1 : b_ih0;
    const float* b_rec = layer ? b_hh1 : b_hh0;
    float* ring_own    = layer ? h2ring : h1ring;
    const int rmask    = layer ? (R2S - 1) : (R1S - 1);

    const int lane = tid & 63;
    const int wv   = tid >> 6;     // 0..3
    const int mat  = wv & 1;       // 0: input matrix, 1: recurrent matrix
    const int p    = wv >> 1;      // k half
    const int kc   = lane & 7;     // k-chunk: floats kc*4 + q*32, q=0..7
    const int r2   = lane >> 3;    // row-pair 0..7 -> rows 2*r2, 2*r2+1

    // fused-phase mapping: this lane reduces gate-row rr for batch bred
    const int rr   = lane & 15;          // gate-row 0..15 (gate = rr>>2, jj = rr&3)
    const int bred = wv * 4 + (lane >> 4);  // batch 0..15

    // ---- one-time: weights -> 64 VGPRs/thread (2 rows x 8 float4) ----
    float4 wreg[2][8];
    {
        #pragma unroll
        for (int i = 0; i < 2; ++i) {
            const int r = r2 * 2 + i;
            const int gate = r >> 2, jj = r & 3;
            const int grow = gate * HH + lw * 4 + jj;
            const float* wsrc = (mat ? w_rec : w_in) + (size_t)grow * HH + p * 256 + kc * 4;
            #pragma unroll
            for (int q = 0; q < 8; ++q)
                wreg[i][q] = *(const float4*)(wsrc + q * 32);
        }
    }
    if (tid < 16) {
        const int g2 = tid >> 2, j2 = tid & 3;
        const int gr = g2 * HH + lw * 4 + j2;
        bias_lds[tid] = b_in[gr] + b_rec[gr];
    }
    if (tid == 0) wdone = 0;
    // c state: lanes rr<4 of every wave hold c for (batch bred, col lw*4+rr)
    float c_reg = 0.f;
    if (rr < 4)
        c_reg = c0[(size_t)layer * BB * HH + (size_t)bred * HH + lw * 4 + rr];
    // pre-stage x(0) (L0, input waves): each wave stages its own k-columns of all b rows
    if (layer == 0 && mat == 0) {
        #pragma unroll
        for (int b = 0; b < 16; ++b)
            gl_lds16(x + ((size_t)b * TT) * HH + p * 256 + lane * 4,
                     act0 + b * HH + p * 256);
    }
    __syncthreads();

    // slot rotation: bijective per row (sum over slots is order-free); with the
    // [b][row][slot] layout, write banks are <=2-way (free), fused reads 0-way.
    const int slot = ((mat << 4) + (p << 3) + kc + (r2 << 2)) & 31;

    auto compute_half = [&](const float* abase) {
        const float* ab0 = abase + p * 256 + kc * 4;
        // partial[(b*16 + row)*33 + slot], rows 2*r2 and 2*r2+1
        float* pwA = partial + (size_t)(2 * r2) * 33 + slot;
        float* pwB = pwA + 33;
        for (int b = 0; b < 16; ++b) {
            const float* ab = ab0 + (size_t)b * HH;
            float x0 = 0.f, y0 = 0.f, z0 = 0.f, w0 = 0.f;
            float x1 = 0.f, y1 = 0.f, z1 = 0.f, w1 = 0.f;
            #pragma unroll
            for (int q = 0; q < 8; ++q) {
                float4 av = *(const float4*)(ab + q * 32);
                x0 += wreg[0][q].x * av.x;
                y0 += wreg[0][q].y * av.y;
                z0 += wreg[0][q].z * av.z;
                w0 += wreg[0][q].w * av.w;
                x1 += wreg[1][q].x * av.x;
                y1 += wreg[1][q].y * av.y;
                z1 += wreg[1][q].z * av.z;
                w1 += wreg[1][q].w * av.w;
            }
            pwA[(size_t)b * 528] = (x0 + y0) + (z0 + w0);   // 528 = 16*33
            pwB[(size_t)b * 528] = (x1 + y1) + (z1 + w1);
        }
    };

    for (int t = 0; t < TT; ++t) {
        // ======== phase A: per-wave specialized (no cross-wave deps) ========
        if (mat == 0) {
            if (layer == 1) {
                poll_bank(flags, 0, t + 1);                    // h1(t) published by all L0
                const float* s0 = h1ring + (size_t)(t & (R1S - 1)) * BB * HH;
                stage_half_sc1(s0, act0, p, lane);
            }
            asm volatile("s_waitcnt vmcnt(0)" ::: "memory");   // x prefetch (L0) staged
            compute_half(act0 + ((layer == 0) ? (t & 1) * BB * HH : 0));
        } else {
            if (t == 0) {
                const float* s1 = h0 + (size_t)layer * BB * HH;
                #pragma unroll
                for (int b = 0; b < 16; ++b)
                    gl_lds16(s1 + (size_t)b * HH + p * 256 + lane * 4,
                             act1 + b * HH + p * 256);
                asm volatile("s_waitcnt vmcnt(0)" ::: "memory");
            } else {
                if (layer == 0) {
                    poll_bank(flags, 0, t);                    // h1(t-1) published
                    if (t >= R1S) poll_bank(flags, 128, t - (R1S - 1));  // ring safety
                } else {
                    poll_bank(flags, 128, t);                  // h2(t-1) published
                }
                const float* s1 = ring_own + (size_t)((t - 1) & rmask) * BB * HH;
                stage_half_sc1(s1, act1, p, lane);
            }
            compute_half(act1);
        }
        __syncthreads();   // B1: partial ds_writes -> fused reads

        // ======== fused: reduce + gates + publish (all 4 waves in parallel) ========
        {
            const float* pp = partial + (size_t)(bred * 16 + rr) * 33;
            float s0 = bias_lds[rr], s1 = 0.f, s2 = 0.f, s3 = 0.f;
            #pragma unroll
            for (int q = 0; q < 32; q += 4) {
                s0 += pp[q + 0];
                s1 += pp[q + 1];
                s2 += pp[q + 2];
                s3 += pp[q + 3];
            }
            const float gsum = (s0 + s1) + (s2 + s3);
            // per-lane nonlinearity: rows 0..3=i, 4..7=f, 8..11=g(tanh), 12..15=o
            const int s = rr >> 2;
            const float gv = (s == 2) ? tanh_f(gsum) : sigmoid_f(gsum);
            // gather i,f,g,o to the s=0 lanes (xor distances 4/8/12 within wave)
            const float t1 = __shfl_xor(gv, 4);
            const float t2 = __shfl_xor(gv, 8);
            const float t3 = __shfl_xor(gv, 12);
            if (rr < 4) {
                const int jj = rr;
                c_reg = t1 * c_reg + gv * t2;                  // f*c + i*g
                const float h_ = t3 * tanh_f(c_reg);           // o*tanh(c)
                float* dst = ring_own + (size_t)(t & rmask) * BB * HH
                           + (size_t)bred * HH + lw * 4 + jj;
                __hip_atomic_store(dst, h_, __ATOMIC_RELAXED, __HIP_MEMORY_SCOPE_AGENT);
                if (t == TT - 1)
                    out[(size_t)layer * BB * HH + (size_t)bred * HH + lw * 4 + jj] = h_;
            }
            // per-wave release: own h stores complete at LLC, then count; the
            // LAST wave (counter reaches 4*(t+1)) stores the single WG flag.
            asm volatile("s_waitcnt vmcnt(0)" ::: "memory");
            if (lane == 0) {
                const int old = atomicAdd(&wdone, 1);
                if (old == 4 * t + 3)
                    __hip_atomic_store(&flags[wg], t + 1, __ATOMIC_RELAXED, __HIP_MEMORY_SCOPE_AGENT);
            }
        }
        // x(t+1) prefetch AFTER the release path; drained at B2' (same as R7's B3).
        if (layer == 0 && mat == 0 && t + 1 < TT) {
            float* l0 = act0 + ((t + 1) & 1) * BB * HH;
            #pragma unroll
            for (int b = 0; b < 16; ++b)
                gl_lds16(x + ((size_t)b * TT + (t + 1)) * HH + p * 256 + lane * 4,
                         l0 + b * HH + p * 256);
        }
        __syncthreads();   // B2': fused reads(t) -> phase-A(t+1) partial writes;
                           // also aligns all waves before the next poll window.
    }
}

extern "C" void kernel_launch(void* const* d_in, const int* in_sizes, int n_in,
                              void* d_out, int out_size, void* d_ws, size_t ws_size,
                              hipStream_t stream) {
    const float* xp   = (const float*)d_in[0];
    const float* h0p  = (const float*)d_in[1];
    const float* c0p  = (const float*)d_in[2];
    const float* wih0 = (const float*)d_in[3];
    const float* whh0 = (const float*)d_in[4];
    const float* bih0 = (const float*)d_in[5];
    const float* bhh0 = (const float*)d_in[6];
    const float* wih1 = (const float*)d_in[7];
    const float* whh1 = (const float*)d_in[8];
    const float* bih1 = (const float*)d_in[9];
    const float* bhh1 = (const float*)d_in[10];
    float* outp = (float*)d_out;

    int*   flags  = (int*)d_ws;                        // [256]
    float* h1ring = (float*)d_ws + 1024;               // 4 KB offset; 128 KB
    float* h2ring = h1ring + R1S * BB * HH;            // 64 KB

    hipMemsetAsync(d_ws, 0, 4096, stream);             // zero flags

    void* args[] = { &xp, &h0p, &c0p, &wih0, &whh0, &bih0, &bhh0,
                     &wih1, &whh1, &bih1, &bhh1, &outp, &flags, &h1ring, &h2ring };
    hipLaunchCooperativeKernel(lstm2_flow10, dim3(256), dim3(256), args, 0, stream);
}